// Round 11
// baseline (527.926 us; speedup 1.0000x reference)
//
#include <hip/hip_runtime.h>
#include <hip/hip_bf16.h>
#include <stdint.h>

#define BB 4
#define SEQ 2048
#define DIM 1024
#define NH 16
#define DH 64
#define MM (BB*SEQ)   // 8192

typedef unsigned short u16;
typedef __attribute__((ext_vector_type(8))) __bf16 bf16x8;
typedef __attribute__((ext_vector_type(4))) float floatx4;
typedef __attribute__((ext_vector_type(16))) float floatx16;
typedef __attribute__((ext_vector_type(2))) float floatx2;
typedef __attribute__((ext_vector_type(4))) unsigned short u16x4;
typedef __attribute__((ext_vector_type(2))) unsigned int uint2v;

// 0.125 * log2(e): folded into Q at projection time
#define QSCALE 0.18033688011112042f

__device__ __forceinline__ u16 f2bf(float f) {
    union { float f; unsigned u; } v; v.f = f;
    unsigned u = v.u;
    u += 0x7FFF + ((u >> 16) & 1);   // RNE
    return (u16)(u >> 16);
}

__device__ __forceinline__ bf16x8 ldb8(const u16* p) {
    return *(const bf16x8*)(const void*)p;
}

__device__ __forceinline__ void async_copy16(const u16* g, u16* l) {
    __builtin_amdgcn_global_load_lds(
        (const __attribute__((address_space(1))) unsigned int*)g,
        (__attribute__((address_space(3))) unsigned int*)l, 16, 0, 0);
}

__device__ __forceinline__ floatx16 mfma32(bf16x8 a, bf16x8 b, floatx16 c) {
    return __builtin_amdgcn_mfma_f32_32x32x16_bf16(a, b, c, 0, 0, 0);
}

__device__ __forceinline__ unsigned cvtpk(float lo, float hi) {
    unsigned r;
    asm("v_cvt_pk_bf16_f32 %0, %1, %2" : "=v"(r) : "v"(lo), "v"(hi));
    return r;
}

// ---------------- prep (merged): x fp32->bf16 ; W fp32 [k][n] -> Wt bf16 [n][k]
__global__ __launch_bounds__(256)
void prep(const float* __restrict__ x, u16* __restrict__ xb,
          const float* __restrict__ Wq, const float* __restrict__ Wk,
          const float* __restrict__ Wv, u16* __restrict__ Wt) {
    const int bx = blockIdx.x;
    const int tid = threadIdx.x;
    if (bx < 8192) {
        const size_t i = ((size_t)bx * 256 + tid) * 4;
        float4 f = *(const float4*)(x + i);
        u16x4 o = { f2bf(f.x), f2bf(f.y), f2bf(f.z), f2bf(f.w) };
        *(u16x4*)(xb + i) = o;
        return;
    }
    const int idx = bx - 8192;          // 0..767 = 16 x 16 x 3
    const int t = idx >> 8;
    const int r2 = idx & 255;
    const int k0 = (r2 >> 4) * 64, n0 = (r2 & 15) * 64;
    const float* W = (t == 0) ? Wq : (t == 1) ? Wk : Wv;
    u16* D = Wt + (size_t)t * DIM * DIM;
    __shared__ u16 T[64][65];
    #pragma unroll
    for (int p = 0; p < 4; p++) {
        const int r = p * 16 + (tid >> 4), c = (tid & 15) * 4;
        float4 f = *(const float4*)(W + (size_t)(k0 + r) * DIM + n0 + c);
        T[c + 0][r] = f2bf(f.x); T[c + 1][r] = f2bf(f.y);
        T[c + 2][r] = f2bf(f.z); T[c + 3][r] = f2bf(f.w);
    }
    __syncthreads();
    #pragma unroll
    for (int p = 0; p < 4; p++) {
        const int rn = p * 16 + (tid >> 4), ck = (tid & 15) * 4;
        u16x4 v = { T[rn][ck], T[rn][ck + 1], T[rn][ck + 2], T[rn][ck + 3] };
        *(u16x4*)(D + (size_t)(n0 + rn) * DIM + k0 + ck) = v;
    }
}

// ---------------- Phase 1: merged-QKV bf16 GEMM, shared-A LDS, 12 waves --------
// qkv_gemm3m: one 768-thread block computes Q, K AND V for a (m0,c0) tile.
// 3 wave-groups of 4; group tg runs gemm3's exact per-wave compute against a
// SHARED A double-buffer (staged once, was 3x) + its own B buffer. LDS 64 KB
// -> 2 blocks/CU -> 24 waves/CU (6/SIMD, 2x gemm3's latency-hiding pool);
// independent blocks' barriers interleave across the per-iter DMA drain.
// outputs: Q[bh][n][d] (pre-scaled), K[bh][n][d], Vt[bh][d][n]
__global__ __launch_bounds__(768, 6)
void qkv_gemm3m(const u16* __restrict__ xb, const u16* __restrict__ Wt,
                const float* __restrict__ bq, const float* __restrict__ bk,
                const float* __restrict__ bv, u16* __restrict__ ws) {
    __shared__ u16 As[2][4096];
    __shared__ u16 Bs[3][2][4096];

    const int m0 = blockIdx.x * 128;
    const int c0 = blockIdx.y * 128;

    const int tid  = threadIdx.x;
    const int lane = tid & 63;
    const int w    = tid >> 6;        // 0..11
    const int tg   = w >> 2;          // 0..2  (Q/K/V group)
    const int wl   = w & 3;           // wave within group
    const int wr = wl >> 1, wc = wl & 1;
    const int g = lane >> 4, ln = lane & 15;

    const u16* Wtb = Wt + (size_t)tg * DIM * DIM;
    const float* bias = (tg == 0) ? bq : (tg == 1) ? bk : bv;
    const float osc = (tg == 0) ? QSCALE : 1.0f;
    u16* dst = ws + (size_t)tg * ((size_t)MM * DIM);

    floatx4 acc[4][4];
    #pragma unroll
    for (int i = 0; i < 4; i++)
        #pragma unroll
        for (int j = 0; j < 4; j++) acc[i][j] = (floatx4){0.f,0.f,0.f,0.f};

    const int srow = wl*16 + (lane >> 2);
    const int gseg = (lane & 3) ^ ((lane >> 3) & 3);
    const u16* gA = xb  + (size_t)(m0 + srow) * DIM + gseg*8;
    const u16* gB = Wtb + (size_t)(c0 + srow) * DIM + gseg*8;

    // stage tile 0: group 0 stages shared A; every group stages its own B
    if (tg == 0) {
        async_copy16(gA,                  &As[0][wl*512]);
        async_copy16(gA + (size_t)64*DIM, &As[0][2048 + wl*512]);
    }
    async_copy16(gB,                  &Bs[tg][0][wl*512]);
    async_copy16(gB + (size_t)64*DIM, &Bs[tg][0][2048 + wl*512]);
    __syncthreads();

    const int xu = (ln >> 1) & 3;

    for (int it = 0; it < 32; it++) {
        const int cur = it & 1;
        if (it < 31) {
            const int nxt = cur ^ 1;
            const int kk = (it + 1) * 32;
            if (tg == 0) {
                async_copy16(gA + kk,                  &As[nxt][wl*512]);
                async_copy16(gA + kk + (size_t)64*DIM, &As[nxt][2048 + wl*512]);
            }
            async_copy16(gB + kk,                  &Bs[tg][nxt][wl*512]);
            async_copy16(gB + kk + (size_t)64*DIM, &Bs[tg][nxt][2048 + wl*512]);
        }

        bf16x8 a[4], b[4];
        #pragma unroll
        for (int fr = 0; fr < 4; fr++)
            a[fr] = ldb8(&As[cur][(wr*64 + fr*16 + ln)*32 + (g ^ xu)*8]);
        #pragma unroll
        for (int fc = 0; fc < 4; fc++)
            b[fc] = ldb8(&Bs[tg][cur][(wc*64 + fc*16 + ln)*32 + (g ^ xu)*8]);

        if (tg < 2) {
            #pragma unroll
            for (int fr = 0; fr < 4; fr++)
                #pragma unroll
                for (int fc = 0; fc < 4; fc++)
                    acc[fr][fc] = __builtin_amdgcn_mfma_f32_16x16x32_bf16(
                        b[fc], a[fr], acc[fr][fc], 0, 0, 0);
        } else {
            #pragma unroll
            for (int fr = 0; fr < 4; fr++)
                #pragma unroll
                for (int fc = 0; fc < 4; fc++)
                    acc[fr][fc] = __builtin_amdgcn_mfma_f32_16x16x32_bf16(
                        a[fr], b[fc], acc[fr][fc], 0, 0, 0);
        }
        __syncthreads();
    }

    if (tg < 2) {
        #pragma unroll
        for (int fc = 0; fc < 4; fc++) {
            const int cc = c0 + wc*64 + fc*16 + g*4;
            const float4 b4 = *(const float4*)&bias[cc];
            const int h = cc >> 6, d = cc & 63;
            #pragma unroll
            for (int fr = 0; fr < 4; fr++) {
                const int tok = m0 + wr*64 + fr*16 + ln;
                const int bidx = tok >> 11, nn = tok & 2047;
                u16x4 v = { f2bf((acc[fr][fc][0] + b4.x) * osc),
                            f2bf((acc[fr][fc][1] + b4.y) * osc),
                            f2bf((acc[fr][fc][2] + b4.z) * osc),
                            f2bf((acc[fr][fc][3] + b4.w) * osc) };
                *(u16x4*)&dst[((size_t)(bidx*NH + h)*SEQ + nn)*DH + d] = v;
            }
        }
    } else {
        #pragma unroll
        for (int fc = 0; fc < 4; fc++) {
            const int cc = c0 + wc*64 + fc*16 + ln;
            const float bias_v = bias[cc];
            const int h = cc >> 6, d = cc & 63;
            #pragma unroll
            for (int fr = 0; fr < 4; fr++) {
                const int mrow = m0 + wr*64 + fr*16 + g*4;
                const int bidx = mrow >> 11, nn = mrow & 2047;
                u16x4 v = { f2bf(acc[fr][fc][0] + bias_v), f2bf(acc[fr][fc][1] + bias_v),
                            f2bf(acc[fr][fc][2] + bias_v), f2bf(acc[fr][fc][3] + bias_v) };
                *(u16x4*)&dst[((size_t)(bidx*NH + h)*DH + d)*SEQ + nn] = v;
            }
        }
    }
}

// ---------------- Phase 1 (fallback, fp32 inputs, small ws) ----------------
#define LDA 40
__global__ __launch_bounds__(256)
void qkv_gemm(const float* __restrict__ x,
              const float* __restrict__ Wq, const float* __restrict__ bq,
              const float* __restrict__ Wk, const float* __restrict__ bk,
              const float* __restrict__ Wv, const float* __restrict__ bv,
              u16* __restrict__ ws) {
    __shared__ u16 As[128 * LDA];
    __shared__ u16 Bs[128 * LDA];
    const int m0 = blockIdx.x * 128;
    const int t  = blockIdx.y >> 3;
    const int c0 = (blockIdx.y & 7) * 128;
    const float* W    = (t == 0) ? Wq : (t == 1) ? Wk : Wv;
    const float* bias = (t == 0) ? bq : (t == 1) ? bk : bv;
    const float osc = (t == 0) ? QSCALE : 1.0f;
    u16* dst = ws + (size_t)t * ((size_t)MM * DIM);
    const int tid  = threadIdx.x;
    const int lane = tid & 63;
    const int wave = tid >> 6;
    const int wr = wave >> 1, wc = wave & 1;
    const int g = lane >> 4, ln = lane & 15;
    floatx4 acc[4][4];
    #pragma unroll
    for (int i = 0; i < 4; i++)
        #pragma unroll
        for (int j = 0; j < 4; j++) acc[i][j] = (floatx4){0.f,0.f,0.f,0.f};
    const int ar  = tid >> 1;
    const int ak  = (tid & 1) * 16;
    const int bkr = tid & 31;
    const int bc  = (tid >> 5) * 16;
    for (int kk = 0; kk < DIM; kk += 32) {
        {
            const float4* s4 = (const float4*)(x + (size_t)(m0 + ar) * DIM + kk + ak);
            float4 f0 = s4[0], f1 = s4[1], f2 = s4[2], f3 = s4[3];
            unsigned pk[8];
            pk[0] = f2bf(f0.x) | ((unsigned)f2bf(f0.y) << 16);
            pk[1] = f2bf(f0.z) | ((unsigned)f2bf(f0.w) << 16);
            pk[2] = f2bf(f1.x) | ((unsigned)f2bf(f1.y) << 16);
            pk[3] = f2bf(f1.z) | ((unsigned)f2bf(f1.w) << 16);
            pk[4] = f2bf(f2.x) | ((unsigned)f2bf(f2.y) << 16);
            pk[5] = f2bf(f2.z) | ((unsigned)f2bf(f2.w) << 16);
            pk[6] = f2bf(f3.x) | ((unsigned)f2bf(f3.y) << 16);
            pk[7] = f2bf(f3.z) | ((unsigned)f2bf(f3.w) << 16);
            uint4* d = (uint4*)&As[ar * LDA + ak];
            d[0] = make_uint4(pk[0], pk[1], pk[2], pk[3]);
            d[1] = make_uint4(pk[4], pk[5], pk[6], pk[7]);
        }
        {
            const float4* s4 = (const float4*)(W + (size_t)(kk + bkr) * DIM + c0 + bc);
            float4 f0 = s4[0], f1 = s4[1], f2 = s4[2], f3 = s4[3];
            float fv[16] = {f0.x,f0.y,f0.z,f0.w, f1.x,f1.y,f1.z,f1.w,
                            f2.x,f2.y,f2.z,f2.w, f3.x,f3.y,f3.z,f3.w};
            #pragma unroll
            for (int j = 0; j < 16; j++)
                Bs[(bc + j) * LDA + bkr] = f2bf(fv[j]);
        }
        __syncthreads();
        bf16x8 a[4], b[4];
        #pragma unroll
        for (int fr = 0; fr < 4; fr++)
            a[fr] = ldb8(&As[(wr*64 + fr*16 + ln) * LDA + g*8]);
        #pragma unroll
        for (int fc = 0; fc < 4; fc++)
            b[fc] = ldb8(&Bs[(wc*64 + fc*16 + ln) * LDA + g*8]);
        #pragma unroll
        for (int fr = 0; fr < 4; fr++)
            #pragma unroll
            for (int fc = 0; fc < 4; fc++)
                acc[fr][fc] = __builtin_amdgcn_mfma_f32_16x16x32_bf16(
                    a[fr], b[fc], acc[fr][fc], 0, 0, 0);
        __syncthreads();
    }
    #pragma unroll
    for (int fc = 0; fc < 4; fc++) {
        const int cc = c0 + wc*64 + fc*16 + ln;
        const float bias_v = bias[cc];
        const int h = cc >> 6, d = cc & 63;
        #pragma unroll
        for (int fr = 0; fr < 4; fr++) {
            #pragma unroll
            for (int rr = 0; rr < 4; rr++) {
                const int mrow = m0 + wr*64 + fr*16 + g*4 + rr;
                const int bidx = mrow >> 11, nn = mrow & 2047;
                const float val = (acc[fr][fc][rr] + bias_v) * osc;
                size_t idx;
                if (t < 2) idx = ((size_t)(bidx*NH + h)*SEQ + nn)*DH + d;
                else       idx = ((size_t)(bidx*NH + h)*DH + d)*SEQ + nn;
                dst[idx] = f2bf(val);
            }
        }
    }
}

// ---------------- Phase 2: flash attention, 64 q-rows/wave, in-register P ------
// attn11 (R8 best, 84.2 us): dual q-set compute sharing each K/V fragment read,
// 4-buffer depth-3 counted-vmcnt staging, XCD-aware grid, cvt_pk P pack.
// (setprio variant regressed in R10 -- barrier-locked waves have no role split.)
__global__ __launch_bounds__(256, 2)
void attn11(const u16* __restrict__ ws, float* __restrict__ out) {
    const int bid = blockIdx.x;
    const int qt = bid >> 6;       // 0..7
    const int bh = bid & 63;       // same-XCD group (id mod 8 == bh mod 8)
    const int b  = bh >> 4;
    const int h  = bh & 15;

    const u16* Qw = ws;
    const u16* Kw = ws + (size_t)MM * DIM;
    const u16* Vt = ws + 2 * (size_t)MM * DIM;

    __shared__ u16 Kbuf[4][4096];   // [64 keys][64 d], 16B-unit XOR swizzle
    __shared__ u16 Vbuf[4][4096];   // [64 d][64 keys], same swizzle

    const int tid  = threadIdx.x;
    const int lane = tid & 63;
    const int w    = tid >> 6;          // 0..3
    const int l31  = lane & 31;
    const int hi   = lane >> 5;
    const int c7   = lane & 7;
    const int q0w  = qt*256 + w*64;

    // staging: wave w covers rows w*16..w*16+15 (two 16B copies per lane per buf)
    const int srow = w*16 + (lane >> 3);
    const int sseg = (lane & 7) ^ ((lane >> 3) & 7);
    const u16* kg = Kw + ((size_t)bh*SEQ + srow)*DH + sseg*8;
    const u16* vg = Vt + ((size_t)bh*DH + srow)*SEQ + sseg*8;

    // Q fragments, two q-sets: lane holds q=l31 (+qs*32), d = ds*16 + hi*8 + j
    bf16x8 qf[2][4];
    #pragma unroll
    for (int qs = 0; qs < 2; qs++) {
        const u16* qp = Qw + ((size_t)bh*SEQ + q0w + qs*32 + l31)*DH + hi*8;
        #pragma unroll
        for (int ds = 0; ds < 4; ds++) qf[qs][ds] = ldb8(qp + ds*16);
    }

    floatx16 accO[2][2];   // [qs][fd]
    #pragma unroll
    for (int qs = 0; qs < 2; qs++)
        #pragma unroll
        for (int fd = 0; fd < 2; fd++)
            #pragma unroll
            for (int r = 0; r < 16; r++) accO[qs][fd][r] = 0.f;
    floatx2 lr2[2] = { (floatx2){0.f,0.f}, (floatx2){0.f,0.f} };
    floatx16 fz;
    #pragma unroll
    for (int r = 0; r < 16; r++) fz[r] = 0.f;

    // prologue: stage tiles 0,1,2 (per wave: 2 K + 2 V loads per tile)
    #pragma unroll
    for (int t = 0; t < 3; t++) {
        async_copy16(kg + (size_t)t*64*DH,           &Kbuf[t][w*1024]);
        async_copy16(kg + (size_t)t*64*DH + 8*DH,    &Kbuf[t][w*1024 + 512]);
        async_copy16(vg + (size_t)t*64,              &Vbuf[t][w*1024]);
        async_copy16(vg + (size_t)t*64 + (size_t)8*SEQ, &Vbuf[t][w*1024 + 512]);
    }

    for (int kt = 0; kt < 32; kt++) {
        // tile kt's 4 loads complete; tiles kt+1,kt+2 (8 loads) stay in flight
        if (kt < 30)       asm volatile("s_waitcnt vmcnt(8)" ::: "memory");
        else if (kt == 30) asm volatile("s_waitcnt vmcnt(4)" ::: "memory");
        else               asm volatile("s_waitcnt vmcnt(0)" ::: "memory");
        __builtin_amdgcn_s_barrier();
        __builtin_amdgcn_sched_barrier(0);

        // issue tile kt+3 into buf[(kt+3)&3] (read last at iter kt-1, safe now)
        if (kt < 29) {
            const int t3 = kt + 3;
            async_copy16(kg + (size_t)t3*64*DH,           &Kbuf[t3 & 3][w*1024]);
            async_copy16(kg + (size_t)t3*64*DH + 8*DH,    &Kbuf[t3 & 3][w*1024 + 512]);
            async_copy16(vg + (size_t)t3*64,              &Vbuf[t3 & 3][w*1024]);
            async_copy16(vg + (size_t)t3*64 + (size_t)8*SEQ, &Vbuf[t3 & 3][w*1024 + 512]);
        }

        const u16* Kc = &Kbuf[kt & 3][0];
        const u16* Vc = &Vbuf[kt & 3][0];

        #pragma unroll
        for (int kb = 0; kb < 2; kb++) {
            // ---- K fragments (shared by both q-sets): 4 b128 reads
            const u16* krow = &Kc[(kb*32 + l31)*64];
            bf16x8 kf0 = ldb8(&krow[((0 + hi) ^ c7)*8]);
            bf16x8 kf1 = ldb8(&krow[((2 + hi) ^ c7)*8]);
            bf16x8 kf2 = ldb8(&krow[((4 + hi) ^ c7)*8]);
            bf16x8 kf3 = ldb8(&krow[((6 + hi) ^ c7)*8]);

            // ---- QK^T: two independent 32x32 score tiles off the same K frags
            floatx16 z0 = mfma32(kf0, qf[0][0], fz);
            floatx16 z1 = mfma32(kf0, qf[1][0], fz);
            z0 = mfma32(kf1, qf[0][1], z0);
            z1 = mfma32(kf1, qf[1][1], z1);
            z0 = mfma32(kf2, qf[0][2], z0);
            z1 = mfma32(kf2, qf[1][2], z1);
            z0 = mfma32(kf3, qf[0][3], z0);
            z1 = mfma32(kf3, qf[1][3], z1);

            // ---- softmax numerator + pack, per q-set
            union { unsigned u[4]; bf16x8 v; } bpA0, bpA1, bpB0, bpB1;
            {
                float p[16];
                #pragma unroll
                for (int r = 0; r < 16; r++) p[r] = __builtin_amdgcn_exp2f(z0[r]);
                #pragma unroll
                for (int i = 0; i < 8; i++) lr2[0] += (floatx2){p[2*i], p[2*i+1]};
                unsigned c[8];
                #pragma unroll
                for (int i = 0; i < 8; i++) c[i] = cvtpk(p[2*i], p[2*i+1]);
                uint2v s02 = __builtin_amdgcn_permlane32_swap(c[0], c[2], false, false);
                uint2v s13 = __builtin_amdgcn_permlane32_swap(c[1], c[3], false, false);
                uint2v s46 = __builtin_amdgcn_permlane32_swap(c[4], c[6], false, false);
                uint2v s57 = __builtin_amdgcn_permlane32_swap(c[5], c[7], false, false);
                bpA0.u[0] = s02[0]; bpA0.u[1] = s13[0]; bpA0.u[2] = s02[1]; bpA0.u[3] = s13[1];
                bpA1.u[0] = s46[0]; bpA1.u[1] = s57[0]; bpA1.u[2] = s46[1]; bpA1.u[3] = s57[1];
            }
            {
                float p[16];
                #pragma unroll
                for (int r = 0; r < 16; r++) p[r] = __builtin_amdgcn_exp2f(z1[r]);
                #pragma unroll
                for (int i = 0; i < 8; i++) lr2[1] += (floatx2){p[2*i], p[2*i+1]};
                unsigned c[8];
                #pragma unroll
                for (int i = 0; i < 8; i++) c[i] = cvtpk(p[2*i], p[2*i+1]);
                uint2v s02 = __builtin_amdgcn_permlane32_swap(c[0], c[2], false, false);
                uint2v s13 = __builtin_amdgcn_permlane32_swap(c[1], c[3], false, false);
                uint2v s46 = __builtin_amdgcn_permlane32_swap(c[4], c[6], false, false);
                uint2v s57 = __builtin_amdgcn_permlane32_swap(c[5], c[7], false, false);
                bpB0.u[0] = s02[0]; bpB0.u[1] = s13[0]; bpB0.u[2] = s02[1]; bpB0.u[3] = s13[1];
                bpB1.u[0] = s46[0]; bpB1.u[1] = s57[0]; bpB1.u[2] = s46[1]; bpB1.u[3] = s57[1];
            }

            // ---- V fragments (shared): 4 b128 reads; PV for both q-sets
            bf16x8 av00 = ldb8(&Vc[(0*32 + l31)*64 + ((kb*4 + 0 + hi) ^ c7)*8]);
            bf16x8 av01 = ldb8(&Vc[(0*32 + l31)*64 + ((kb*4 + 2 + hi) ^ c7)*8]);
            bf16x8 av10 = ldb8(&Vc[(1*32 + l31)*64 + ((kb*4 + 0 + hi) ^ c7)*8]);
            bf16x8 av11 = ldb8(&Vc[(1*32 + l31)*64 + ((kb*4 + 2 + hi) ^ c7)*8]);
            accO[0][0] = mfma32(av00, bpA0.v, accO[0][0]);
            accO[1][0] = mfma32(av00, bpB0.v, accO[1][0]);
            accO[0][1] = mfma32(av10, bpA0.v, accO[0][1]);
            accO[1][1] = mfma32(av10, bpB0.v, accO[1][1]);
            accO[0][0] = mfma32(av01, bpA1.v, accO[0][0]);
            accO[1][0] = mfma32(av01, bpB1.v, accO[1][0]);
            accO[0][1] = mfma32(av11, bpA1.v, accO[0][1]);
            accO[1][1] = mfma32(av11, bpB1.v, accO[1][1]);
        }
    }

    // ---- epilogue: per q-set row-sum across hi halves, normalize, write
    #pragma unroll
    for (int qs = 0; qs < 2; qs++) {
        float v = lr2[qs][0] + lr2[qs][1];
        v += __shfl_xor(v, 32, 64);
        const float inv = 1.0f / v;
        const int n = q0w + qs*32 + l31;
        float* orow = &out[((size_t)b*SEQ + n)*DIM + h*DH];
        #pragma unroll
        for (int fd = 0; fd < 2; fd++)
            #pragma unroll
            for (int rp = 0; rp < 4; rp++) {
                const int d = fd*32 + rp*8 + hi*4;
                float4 o = { accO[qs][fd][rp*4+0]*inv, accO[qs][fd][rp*4+1]*inv,
                             accO[qs][fd][rp*4+2]*inv, accO[qs][fd][rp*4+3]*inv };
                *(float4*)&orow[d] = o;
            }
    }
}

extern "C" void kernel_launch(void* const* d_in, const int* in_sizes, int n_in,
                              void* d_out, int out_size, void* d_ws, size_t ws_size,
                              hipStream_t stream) {
    const float* x  = (const float*)d_in[0];
    const float* Wq = (const float*)d_in[1];
    const float* bq = (const float*)d_in[2];
    const float* Wk = (const float*)d_in[3];
    const float* bk = (const float*)d_in[4];
    const float* Wv = (const float*)d_in[5];
    const float* bv = (const float*)d_in[6];
    u16* ws = (u16*)d_ws;
    float* out = (float*)d_out;

    const size_t need = (size_t)4 * MM * DIM * 2 + (size_t)3 * DIM * DIM * 2;
    if (ws_size >= need) {
        u16* xb = ws + (size_t)3 * MM * DIM;
        u16* Wt = ws + (size_t)4 * MM * DIM;
        prep<<<dim3(8192 + 768), 256, 0, stream>>>(x, xb, Wq, Wk, Wv, Wt);
        qkv_gemm3m<<<dim3(MM/128, 8), 768, 0, stream>>>(xb, Wt, bq, bk, bv, ws);
    } else {
        qkv_gemm<<<dim3(MM/128, 24), 256, 0, stream>>>(x, Wq, bq, Wk, bk, Wv, bv, ws);
    }
    attn11<<<dim3((SEQ/256) * NH * BB), 256, 0, stream>>>(ws, out);
}

// Round 12
// 245.763 us; speedup vs baseline: 2.1481x; 2.1481x over previous
//
#include <hip/hip_runtime.h>
#include <hip/hip_bf16.h>
#include <stdint.h>

#define BB 4
#define SEQ 2048
#define DIM 1024
#define NH 16
#define DH 64
#define MM (BB*SEQ)   // 8192

typedef unsigned short u16;
typedef __attribute__((ext_vector_type(8))) __bf16 bf16x8;
typedef __attribute__((ext_vector_type(4))) float floatx4;
typedef __attribute__((ext_vector_type(16))) float floatx16;
typedef __attribute__((ext_vector_type(2))) float floatx2;
typedef __attribute__((ext_vector_type(4))) unsigned short u16x4;
typedef __attribute__((ext_vector_type(2))) unsigned int uint2v;

// 0.125 * log2(e): folded into Q at projection time
#define QSCALE 0.18033688011112042f

__device__ __forceinline__ u16 f2bf(float f) {
    union { float f; unsigned u; } v; v.f = f;
    unsigned u = v.u;
    u += 0x7FFF + ((u >> 16) & 1);   // RNE
    return (u16)(u >> 16);
}

__device__ __forceinline__ bf16x8 ldb8(const u16* p) {
    return *(const bf16x8*)(const void*)p;
}

__device__ __forceinline__ void async_copy16(const u16* g, u16* l) {
    __builtin_amdgcn_global_load_lds(
        (const __attribute__((address_space(1))) unsigned int*)g,
        (__attribute__((address_space(3))) unsigned int*)l, 16, 0, 0);
}

__device__ __forceinline__ floatx16 mfma32(bf16x8 a, bf16x8 b, floatx16 c) {
    return __builtin_amdgcn_mfma_f32_32x32x16_bf16(a, b, c, 0, 0, 0);
}

__device__ __forceinline__ unsigned cvtpk(float lo, float hi) {
    unsigned r;
    asm("v_cvt_pk_bf16_f32 %0, %1, %2" : "=v"(r) : "v"(lo), "v"(hi));
    return r;
}

// ---------------- prep (merged): x fp32->bf16 ; W fp32 [k][n] -> Wt bf16 [n][k]
__global__ __launch_bounds__(256)
void prep(const float* __restrict__ x, u16* __restrict__ xb,
          const float* __restrict__ Wq, const float* __restrict__ Wk,
          const float* __restrict__ Wv, u16* __restrict__ Wt) {
    const int bx = blockIdx.x;
    const int tid = threadIdx.x;
    if (bx < 8192) {
        const size_t i = ((size_t)bx * 256 + tid) * 4;
        float4 f = *(const float4*)(x + i);
        u16x4 o = { f2bf(f.x), f2bf(f.y), f2bf(f.z), f2bf(f.w) };
        *(u16x4*)(xb + i) = o;
        return;
    }
    const int idx = bx - 8192;          // 0..767 = 16 x 16 x 3
    const int t = idx >> 8;
    const int r2 = idx & 255;
    const int k0 = (r2 >> 4) * 64, n0 = (r2 & 15) * 64;
    const float* W = (t == 0) ? Wq : (t == 1) ? Wk : Wv;
    u16* D = Wt + (size_t)t * DIM * DIM;
    __shared__ u16 T[64][65];
    #pragma unroll
    for (int p = 0; p < 4; p++) {
        const int r = p * 16 + (tid >> 4), c = (tid & 15) * 4;
        float4 f = *(const float4*)(W + (size_t)(k0 + r) * DIM + n0 + c);
        T[c + 0][r] = f2bf(f.x); T[c + 1][r] = f2bf(f.y);
        T[c + 2][r] = f2bf(f.z); T[c + 3][r] = f2bf(f.w);
    }
    __syncthreads();
    #pragma unroll
    for (int p = 0; p < 4; p++) {
        const int rn = p * 16 + (tid >> 4), ck = (tid & 15) * 4;
        u16x4 v = { T[rn][ck], T[rn][ck + 1], T[rn][ck + 2], T[rn][ck + 3] };
        *(u16x4*)(D + (size_t)(n0 + rn) * DIM + k0 + ck) = v;
    }
}

// ---------------- Phase 1: merged-QKV bf16 GEMM, shared-A LDS, 12 waves --------
// qkv_gemm3m: one 768-thread block computes Q, K AND V for a (m0,c0) tile.
// 3 wave-groups of 4; group tg runs gemm3's exact per-wave compute against a
// SHARED A double-buffer (staged once, was 3x) + its own B buffer.
// R11 ERRATA: __launch_bounds__(768,6) capped per-wave regs at ~85 (arch split
// -> 40) and spilled acc to scratch (WRITE 1.1GB, 362us). Fixed: no min-waves
// clamp; compiler emits ~84 VGPR, HW occupancy = 6 waves/EU = 24 waves/CU.
// outputs: Q[bh][n][d] (pre-scaled), K[bh][n][d], Vt[bh][d][n]
__global__ __launch_bounds__(768)
void qkv_gemm3m(const u16* __restrict__ xb, const u16* __restrict__ Wt,
                const float* __restrict__ bq, const float* __restrict__ bk,
                const float* __restrict__ bv, u16* __restrict__ ws) {
    __shared__ u16 As[2][4096];
    __shared__ u16 Bs[3][2][4096];

    const int m0 = blockIdx.x * 128;
    const int c0 = blockIdx.y * 128;

    const int tid  = threadIdx.x;
    const int lane = tid & 63;
    const int w    = tid >> 6;        // 0..11
    const int tg   = w >> 2;          // 0..2  (Q/K/V group)
    const int wl   = w & 3;           // wave within group
    const int wr = wl >> 1, wc = wl & 1;
    const int g = lane >> 4, ln = lane & 15;

    const u16* Wtb = Wt + (size_t)tg * DIM * DIM;
    const float* bias = (tg == 0) ? bq : (tg == 1) ? bk : bv;
    const float osc = (tg == 0) ? QSCALE : 1.0f;
    u16* dst = ws + (size_t)tg * ((size_t)MM * DIM);

    floatx4 acc[4][4];
    #pragma unroll
    for (int i = 0; i < 4; i++)
        #pragma unroll
        for (int j = 0; j < 4; j++) acc[i][j] = (floatx4){0.f,0.f,0.f,0.f};

    const int srow = wl*16 + (lane >> 2);
    const int gseg = (lane & 3) ^ ((lane >> 3) & 3);
    const u16* gA = xb  + (size_t)(m0 + srow) * DIM + gseg*8;
    const u16* gB = Wtb + (size_t)(c0 + srow) * DIM + gseg*8;

    // stage tile 0: group 0 stages shared A; every group stages its own B
    if (tg == 0) {
        async_copy16(gA,                  &As[0][wl*512]);
        async_copy16(gA + (size_t)64*DIM, &As[0][2048 + wl*512]);
    }
    async_copy16(gB,                  &Bs[tg][0][wl*512]);
    async_copy16(gB + (size_t)64*DIM, &Bs[tg][0][2048 + wl*512]);
    __syncthreads();

    const int xu = (ln >> 1) & 3;

    for (int it = 0; it < 32; it++) {
        const int cur = it & 1;
        if (it < 31) {
            const int nxt = cur ^ 1;
            const int kk = (it + 1) * 32;
            if (tg == 0) {
                async_copy16(gA + kk,                  &As[nxt][wl*512]);
                async_copy16(gA + kk + (size_t)64*DIM, &As[nxt][2048 + wl*512]);
            }
            async_copy16(gB + kk,                  &Bs[tg][nxt][wl*512]);
            async_copy16(gB + kk + (size_t)64*DIM, &Bs[tg][nxt][2048 + wl*512]);
        }

        bf16x8 a[4], b[4];
        #pragma unroll
        for (int fr = 0; fr < 4; fr++)
            a[fr] = ldb8(&As[cur][(wr*64 + fr*16 + ln)*32 + (g ^ xu)*8]);
        #pragma unroll
        for (int fc = 0; fc < 4; fc++)
            b[fc] = ldb8(&Bs[tg][cur][(wc*64 + fc*16 + ln)*32 + (g ^ xu)*8]);

        if (tg < 2) {
            #pragma unroll
            for (int fr = 0; fr < 4; fr++)
                #pragma unroll
                for (int fc = 0; fc < 4; fc++)
                    acc[fr][fc] = __builtin_amdgcn_mfma_f32_16x16x32_bf16(
                        b[fc], a[fr], acc[fr][fc], 0, 0, 0);
        } else {
            #pragma unroll
            for (int fr = 0; fr < 4; fr++)
                #pragma unroll
                for (int fc = 0; fc < 4; fc++)
                    acc[fr][fc] = __builtin_amdgcn_mfma_f32_16x16x32_bf16(
                        a[fr], b[fc], acc[fr][fc], 0, 0, 0);
        }
        __syncthreads();
    }

    if (tg < 2) {
        #pragma unroll
        for (int fc = 0; fc < 4; fc++) {
            const int cc = c0 + wc*64 + fc*16 + g*4;
            const float4 b4 = *(const float4*)&bias[cc];
            const int h = cc >> 6, d = cc & 63;
            #pragma unroll
            for (int fr = 0; fr < 4; fr++) {
                const int tok = m0 + wr*64 + fr*16 + ln;
                const int bidx = tok >> 11, nn = tok & 2047;
                u16x4 v = { f2bf((acc[fr][fc][0] + b4.x) * osc),
                            f2bf((acc[fr][fc][1] + b4.y) * osc),
                            f2bf((acc[fr][fc][2] + b4.z) * osc),
                            f2bf((acc[fr][fc][3] + b4.w) * osc) };
                *(u16x4*)&dst[((size_t)(bidx*NH + h)*SEQ + nn)*DH + d] = v;
            }
        }
    } else {
        #pragma unroll
        for (int fc = 0; fc < 4; fc++) {
            const int cc = c0 + wc*64 + fc*16 + ln;
            const float bias_v = bias[cc];
            const int h = cc >> 6, d = cc & 63;
            #pragma unroll
            for (int fr = 0; fr < 4; fr++) {
                const int mrow = m0 + wr*64 + fr*16 + g*4;
                const int bidx = mrow >> 11, nn = mrow & 2047;
                u16x4 v = { f2bf(acc[fr][fc][0] + bias_v), f2bf(acc[fr][fc][1] + bias_v),
                            f2bf(acc[fr][fc][2] + bias_v), f2bf(acc[fr][fc][3] + bias_v) };
                *(u16x4*)&dst[((size_t)(bidx*NH + h)*DH + d)*SEQ + nn] = v;
            }
        }
    }
}

// ---------------- Phase 1 (fallback, fp32 inputs, small ws) ----------------
#define LDA 40
__global__ __launch_bounds__(256)
void qkv_gemm(const float* __restrict__ x,
              const float* __restrict__ Wq, const float* __restrict__ bq,
              const float* __restrict__ Wk, const float* __restrict__ bk,
              const float* __restrict__ Wv, const float* __restrict__ bv,
              u16* __restrict__ ws) {
    __shared__ u16 As[128 * LDA];
    __shared__ u16 Bs[128 * LDA];
    const int m0 = blockIdx.x * 128;
    const int t  = blockIdx.y >> 3;
    const int c0 = (blockIdx.y & 7) * 128;
    const float* W    = (t == 0) ? Wq : (t == 1) ? Wk : Wv;
    const float* bias = (t == 0) ? bq : (t == 1) ? bk : bv;
    const float osc = (t == 0) ? QSCALE : 1.0f;
    u16* dst = ws + (size_t)t * ((size_t)MM * DIM);
    const int tid  = threadIdx.x;
    const int lane = tid & 63;
    const int wave = tid >> 6;
    const int wr = wave >> 1, wc = wave & 1;
    const int g = lane >> 4, ln = lane & 15;
    floatx4 acc[4][4];
    #pragma unroll
    for (int i = 0; i < 4; i++)
        #pragma unroll
        for (int j = 0; j < 4; j++) acc[i][j] = (floatx4){0.f,0.f,0.f,0.f};
    const int ar  = tid >> 1;
    const int ak  = (tid & 1) * 16;
    const int bkr = tid & 31;
    const int bc  = (tid >> 5) * 16;
    for (int kk = 0; kk < DIM; kk += 32) {
        {
            const float4* s4 = (const float4*)(x + (size_t)(m0 + ar) * DIM + kk + ak);
            float4 f0 = s4[0], f1 = s4[1], f2 = s4[2], f3 = s4[3];
            unsigned pk[8];
            pk[0] = f2bf(f0.x) | ((unsigned)f2bf(f0.y) << 16);
            pk[1] = f2bf(f0.z) | ((unsigned)f2bf(f0.w) << 16);
            pk[2] = f2bf(f1.x) | ((unsigned)f2bf(f1.y) << 16);
            pk[3] = f2bf(f1.z) | ((unsigned)f2bf(f1.w) << 16);
            pk[4] = f2bf(f2.x) | ((unsigned)f2bf(f2.y) << 16);
            pk[5] = f2bf(f2.z) | ((unsigned)f2bf(f2.w) << 16);
            pk[6] = f2bf(f3.x) | ((unsigned)f2bf(f3.y) << 16);
            pk[7] = f2bf(f3.z) | ((unsigned)f2bf(f3.w) << 16);
            uint4* d = (uint4*)&As[ar * LDA + ak];
            d[0] = make_uint4(pk[0], pk[1], pk[2], pk[3]);
            d[1] = make_uint4(pk[4], pk[5], pk[6], pk[7]);
        }
        {
            const float4* s4 = (const float4*)(W + (size_t)(kk + bkr) * DIM + c0 + bc);
            float4 f0 = s4[0], f1 = s4[1], f2 = s4[2], f3 = s4[3];
            float fv[16] = {f0.x,f0.y,f0.z,f0.w, f1.x,f1.y,f1.z,f1.w,
                            f2.x,f2.y,f2.z,f2.w, f3.x,f3.y,f3.z,f3.w};
            #pragma unroll
            for (int j = 0; j < 16; j++)
                Bs[(bc + j) * LDA + bkr] = f2bf(fv[j]);
        }
        __syncthreads();
        bf16x8 a[4], b[4];
        #pragma unroll
        for (int fr = 0; fr < 4; fr++)
            a[fr] = ldb8(&As[(wr*64 + fr*16 + ln) * LDA + g*8]);
        #pragma unroll
        for (int fc = 0; fc < 4; fc++)
            b[fc] = ldb8(&Bs[(wc*64 + fc*16 + ln) * LDA + g*8]);
        #pragma unroll
        for (int fr = 0; fr < 4; fr++)
            #pragma unroll
            for (int fc = 0; fc < 4; fc++)
                acc[fr][fc] = __builtin_amdgcn_mfma_f32_16x16x32_bf16(
                    a[fr], b[fc], acc[fr][fc], 0, 0, 0);
        __syncthreads();
    }
    #pragma unroll
    for (int fc = 0; fc < 4; fc++) {
        const int cc = c0 + wc*64 + fc*16 + ln;
        const float bias_v = bias[cc];
        const int h = cc >> 6, d = cc & 63;
        #pragma unroll
        for (int fr = 0; fr < 4; fr++) {
            #pragma unroll
            for (int rr = 0; rr < 4; rr++) {
                const int mrow = m0 + wr*64 + fr*16 + g*4 + rr;
                const int bidx = mrow >> 11, nn = mrow & 2047;
                const float val = (acc[fr][fc][rr] + bias_v) * osc;
                size_t idx;
                if (t < 2) idx = ((size_t)(bidx*NH + h)*SEQ + nn)*DH + d;
                else       idx = ((size_t)(bidx*NH + h)*DH + d)*SEQ + nn;
                dst[idx] = f2bf(val);
            }
        }
    }
}

// ---------------- Phase 2: flash attention, 64 q-rows/wave, in-register P ------
// attn11 (R8 best, 84.2 us): dual q-set compute sharing each K/V fragment read,
// 4-buffer depth-3 counted-vmcnt staging, XCD-aware grid, cvt_pk P pack.
__global__ __launch_bounds__(256, 2)
void attn11(const u16* __restrict__ ws, float* __restrict__ out) {
    const int bid = blockIdx.x;
    const int qt = bid >> 6;       // 0..7
    const int bh = bid & 63;       // same-XCD group (id mod 8 == bh mod 8)
    const int b  = bh >> 4;
    const int h  = bh & 15;

    const u16* Qw = ws;
    const u16* Kw = ws + (size_t)MM * DIM;
    const u16* Vt = ws + 2 * (size_t)MM * DIM;

    __shared__ u16 Kbuf[4][4096];   // [64 keys][64 d], 16B-unit XOR swizzle
    __shared__ u16 Vbuf[4][4096];   // [64 d][64 keys], same swizzle

    const int tid  = threadIdx.x;
    const int lane = tid & 63;
    const int w    = tid >> 6;          // 0..3
    const int l31  = lane & 31;
    const int hi   = lane >> 5;
    const int c7   = lane & 7;
    const int q0w  = qt*256 + w*64;

    // staging: wave w covers rows w*16..w*16+15 (two 16B copies per lane per buf)
    const int srow = w*16 + (lane >> 3);
    const int sseg = (lane & 7) ^ ((lane >> 3) & 7);
    const u16* kg = Kw + ((size_t)bh*SEQ + srow)*DH + sseg*8;
    const u16* vg = Vt + ((size_t)bh*DH + srow)*SEQ + sseg*8;

    // Q fragments, two q-sets: lane holds q=l31 (+qs*32), d = ds*16 + hi*8 + j
    bf16x8 qf[2][4];
    #pragma unroll
    for (int qs = 0; qs < 2; qs++) {
        const u16* qp = Qw + ((size_t)bh*SEQ + q0w + qs*32 + l31)*DH + hi*8;
        #pragma unroll
        for (int ds = 0; ds < 4; ds++) qf[qs][ds] = ldb8(qp + ds*16);
    }

    floatx16 accO[2][2];   // [qs][fd]
    #pragma unroll
    for (int qs = 0; qs < 2; qs++)
        #pragma unroll
        for (int fd = 0; fd < 2; fd++)
            #pragma unroll
            for (int r = 0; r < 16; r++) accO[qs][fd][r] = 0.f;
    floatx2 lr2[2] = { (floatx2){0.f,0.f}, (floatx2){0.f,0.f} };
    floatx16 fz;
    #pragma unroll
    for (int r = 0; r < 16; r++) fz[r] = 0.f;

    // prologue: stage tiles 0,1,2 (per wave: 2 K + 2 V loads per tile)
    #pragma unroll
    for (int t = 0; t < 3; t++) {
        async_copy16(kg + (size_t)t*64*DH,           &Kbuf[t][w*1024]);
        async_copy16(kg + (size_t)t*64*DH + 8*DH,    &Kbuf[t][w*1024 + 512]);
        async_copy16(vg + (size_t)t*64,              &Vbuf[t][w*1024]);
        async_copy16(vg + (size_t)t*64 + (size_t)8*SEQ, &Vbuf[t][w*1024 + 512]);
    }

    for (int kt = 0; kt < 32; kt++) {
        // tile kt's 4 loads complete; tiles kt+1,kt+2 (8 loads) stay in flight
        if (kt < 30)       asm volatile("s_waitcnt vmcnt(8)" ::: "memory");
        else if (kt == 30) asm volatile("s_waitcnt vmcnt(4)" ::: "memory");
        else               asm volatile("s_waitcnt vmcnt(0)" ::: "memory");
        __builtin_amdgcn_s_barrier();
        __builtin_amdgcn_sched_barrier(0);

        // issue tile kt+3 into buf[(kt+3)&3] (read last at iter kt-1, safe now)
        if (kt < 29) {
            const int t3 = kt + 3;
            async_copy16(kg + (size_t)t3*64*DH,           &Kbuf[t3 & 3][w*1024]);
            async_copy16(kg + (size_t)t3*64*DH + 8*DH,    &Kbuf[t3 & 3][w*1024 + 512]);
            async_copy16(vg + (size_t)t3*64,              &Vbuf[t3 & 3][w*1024]);
            async_copy16(vg + (size_t)t3*64 + (size_t)8*SEQ, &Vbuf[t3 & 3][w*1024 + 512]);
        }

        const u16* Kc = &Kbuf[kt & 3][0];
        const u16* Vc = &Vbuf[kt & 3][0];

        #pragma unroll
        for (int kb = 0; kb < 2; kb++) {
            // ---- K fragments (shared by both q-sets): 4 b128 reads
            const u16* krow = &Kc[(kb*32 + l31)*64];
            bf16x8 kf0 = ldb8(&krow[((0 + hi) ^ c7)*8]);
            bf16x8 kf1 = ldb8(&krow[((2 + hi) ^ c7)*8]);
            bf16x8 kf2 = ldb8(&krow[((4 + hi) ^ c7)*8]);
            bf16x8 kf3 = ldb8(&krow[((6 + hi) ^ c7)*8]);

            // ---- QK^T: two independent 32x32 score tiles off the same K frags
            floatx16 z0 = mfma32(kf0, qf[0][0], fz);
            floatx16 z1 = mfma32(kf0, qf[1][0], fz);
            z0 = mfma32(kf1, qf[0][1], z0);
            z1 = mfma32(kf1, qf[1][1], z1);
            z0 = mfma32(kf2, qf[0][2], z0);
            z1 = mfma32(kf2, qf[1][2], z1);
            z0 = mfma32(kf3, qf[0][3], z0);
            z1 = mfma32(kf3, qf[1][3], z1);

            // ---- softmax numerator + pack, per q-set
            union { unsigned u[4]; bf16x8 v; } bpA0, bpA1, bpB0, bpB1;
            {
                float p[16];
                #pragma unroll
                for (int r = 0; r < 16; r++) p[r] = __builtin_amdgcn_exp2f(z0[r]);
                #pragma unroll
                for (int i = 0; i < 8; i++) lr2[0] += (floatx2){p[2*i], p[2*i+1]};
                unsigned c[8];
                #pragma unroll
                for (int i = 0; i < 8; i++) c[i] = cvtpk(p[2*i], p[2*i+1]);
                uint2v s02 = __builtin_amdgcn_permlane32_swap(c[0], c[2], false, false);
                uint2v s13 = __builtin_amdgcn_permlane32_swap(c[1], c[3], false, false);
                uint2v s46 = __builtin_amdgcn_permlane32_swap(c[4], c[6], false, false);
                uint2v s57 = __builtin_amdgcn_permlane32_swap(c[5], c[7], false, false);
                bpA0.u[0] = s02[0]; bpA0.u[1] = s13[0]; bpA0.u[2] = s02[1]; bpA0.u[3] = s13[1];
                bpA1.u[0] = s46[0]; bpA1.u[1] = s57[0]; bpA1.u[2] = s46[1]; bpA1.u[3] = s57[1];
            }
            {
                float p[16];
                #pragma unroll
                for (int r = 0; r < 16; r++) p[r] = __builtin_amdgcn_exp2f(z1[r]);
                #pragma unroll
                for (int i = 0; i < 8; i++) lr2[1] += (floatx2){p[2*i], p[2*i+1]};
                unsigned c[8];
                #pragma unroll
                for (int i = 0; i < 8; i++) c[i] = cvtpk(p[2*i], p[2*i+1]);
                uint2v s02 = __builtin_amdgcn_permlane32_swap(c[0], c[2], false, false);
                uint2v s13 = __builtin_amdgcn_permlane32_swap(c[1], c[3], false, false);
                uint2v s46 = __builtin_amdgcn_permlane32_swap(c[4], c[6], false, false);
                uint2v s57 = __builtin_amdgcn_permlane32_swap(c[5], c[7], false, false);
                bpB0.u[0] = s02[0]; bpB0.u[1] = s13[0]; bpB0.u[2] = s02[1]; bpB0.u[3] = s13[1];
                bpB1.u[0] = s46[0]; bpB1.u[1] = s57[0]; bpB1.u[2] = s46[1]; bpB1.u[3] = s57[1];
            }

            // ---- V fragments (shared): 4 b128 reads; PV for both q-sets
            bf16x8 av00 = ldb8(&Vc[(0*32 + l31)*64 + ((kb*4 + 0 + hi) ^ c7)*8]);
            bf16x8 av01 = ldb8(&Vc[(0*32 + l31)*64 + ((kb*4 + 2 + hi) ^ c7)*8]);
            bf16x8 av10 = ldb8(&Vc[(1*32 + l31)*64 + ((kb*4 + 0 + hi) ^ c7)*8]);
            bf16x8 av11 = ldb8(&Vc[(1*32 + l31)*64 + ((kb*4 + 2 + hi) ^ c7)*8]);
            accO[0][0] = mfma32(av00, bpA0.v, accO[0][0]);
            accO[1][0] = mfma32(av00, bpB0.v, accO[1][0]);
            accO[0][1] = mfma32(av10, bpA0.v, accO[0][1]);
            accO[1][1] = mfma32(av10, bpB0.v, accO[1][1]);
            accO[0][0] = mfma32(av01, bpA1.v, accO[0][0]);
            accO[1][0] = mfma32(av01, bpB1.v, accO[1][0]);
            accO[0][1] = mfma32(av11, bpA1.v, accO[0][1]);
            accO[1][1] = mfma32(av11, bpB1.v, accO[1][1]);
        }
    }

    // ---- epilogue: per q-set row-sum across hi halves, normalize, write
    #pragma unroll
    for (int qs = 0; qs < 2; qs++) {
        float v = lr2[qs][0] + lr2[qs][1];
        v += __shfl_xor(v, 32, 64);
        const float inv = 1.0f / v;
        const int n = q0w + qs*32 + l31;
        float* orow = &out[((size_t)b*SEQ + n)*DIM + h*DH];
        #pragma unroll
        for (int fd = 0; fd < 2; fd++)
            #pragma unroll
            for (int rp = 0; rp < 4; rp++) {
                const int d = fd*32 + rp*8 + hi*4;
                float4 o = { accO[qs][fd][rp*4+0]*inv, accO[qs][fd][rp*4+1]*inv,
                             accO[qs][fd][rp*4+2]*inv, accO[qs][fd][rp*4+3]*inv };
                *(float4*)&orow[d] = o;
            }
    }
}

extern "C" void kernel_launch(void* const* d_in, const int* in_sizes, int n_in,
                              void* d_out, int out_size, void* d_ws, size_t ws_size,
                              hipStream_t stream) {
    const float* x  = (const float*)d_in[0];
    const float* Wq = (const float*)d_in[1];
    const float* bq = (const float*)d_in[2];
    const float* Wk = (const float*)d_in[3];
    const float* bk = (const float*)d_in[4];
    const float* Wv = (const float*)d_in[5];
    const float* bv = (const float*)d_in[6];
    u16* ws = (u16*)d_ws;
    float* out = (float*)d_out;

    const size_t need = (size_t)4 * MM * DIM * 2 + (size_t)3 * DIM * DIM * 2;
    if (ws_size >= need) {
        u16* xb = ws + (size_t)3 * MM * DIM;
        u16* Wt = ws + (size_t)4 * MM * DIM;
        prep<<<dim3(8192 + 768), 256, 0, stream>>>(x, xb, Wq, Wk, Wv, Wt);
        qkv_gemm3m<<<dim3(MM/128, 8), 768, 0, stream>>>(xb, Wt, bq, bk, bv, ws);
    } else {
        qkv_gemm<<<dim3(MM/128, 24), 256, 0, stream>>>(x, Wq, bq, Wk, bk, Wv, bv, ws);
    }
    attn11<<<dim3((SEQ/256) * NH * BB), 256, 0, stream>>>(ws, out);
}

// Round 13
// 242.654 us; speedup vs baseline: 2.1756x; 1.0128x over previous
//
#include <hip/hip_runtime.h>
#include <hip/hip_bf16.h>
#include <stdint.h>

#define BB 4
#define SEQ 2048
#define DIM 1024
#define NH 16
#define DH 64
#define MM (BB*SEQ)   // 8192

typedef unsigned short u16;
typedef __attribute__((ext_vector_type(8))) __bf16 bf16x8;
typedef __attribute__((ext_vector_type(4))) float floatx4;
typedef __attribute__((ext_vector_type(16))) float floatx16;
typedef __attribute__((ext_vector_type(2))) float floatx2;
typedef __attribute__((ext_vector_type(4))) unsigned short u16x4;
typedef __attribute__((ext_vector_type(2))) unsigned int uint2v;

// 0.125 * log2(e): folded into Q at projection time
#define QSCALE 0.18033688011112042f

__device__ __forceinline__ u16 f2bf(float f) {
    union { float f; unsigned u; } v; v.f = f;
    unsigned u = v.u;
    u += 0x7FFF + ((u >> 16) & 1);   // RNE
    return (u16)(u >> 16);
}

__device__ __forceinline__ bf16x8 ldb8(const u16* p) {
    return *(const bf16x8*)(const void*)p;
}

__device__ __forceinline__ void async_copy16(const u16* g, u16* l) {
    __builtin_amdgcn_global_load_lds(
        (const __attribute__((address_space(1))) unsigned int*)g,
        (__attribute__((address_space(3))) unsigned int*)l, 16, 0, 0);
}

__device__ __forceinline__ floatx16 mfma32(bf16x8 a, bf16x8 b, floatx16 c) {
    return __builtin_amdgcn_mfma_f32_32x32x16_bf16(a, b, c, 0, 0, 0);
}

__device__ __forceinline__ unsigned cvtpk(float lo, float hi) {
    unsigned r;
    asm("v_cvt_pk_bf16_f32 %0, %1, %2" : "=v"(r) : "v"(lo), "v"(hi));
    return r;
}

// ---------------- prep (merged): x fp32->bf16 ; W fp32 [k][n] -> Wt bf16 [n][k]
__global__ __launch_bounds__(256)
void prep(const float* __restrict__ x, u16* __restrict__ xb,
          const float* __restrict__ Wq, const float* __restrict__ Wk,
          const float* __restrict__ Wv, u16* __restrict__ Wt) {
    const int bx = blockIdx.x;
    const int tid = threadIdx.x;
    if (bx < 8192) {
        const size_t i = ((size_t)bx * 256 + tid) * 4;
        float4 f = *(const float4*)(x + i);
        u16x4 o = { f2bf(f.x), f2bf(f.y), f2bf(f.z), f2bf(f.w) };
        *(u16x4*)(xb + i) = o;
        return;
    }
    const int idx = bx - 8192;          // 0..767 = 16 x 16 x 3
    const int t = idx >> 8;
    const int r2 = idx & 255;
    const int k0 = (r2 >> 4) * 64, n0 = (r2 & 15) * 64;
    const float* W = (t == 0) ? Wq : (t == 1) ? Wk : Wv;
    u16* D = Wt + (size_t)t * DIM * DIM;
    __shared__ u16 T[64][65];
    #pragma unroll
    for (int p = 0; p < 4; p++) {
        const int r = p * 16 + (tid >> 4), c = (tid & 15) * 4;
        float4 f = *(const float4*)(W + (size_t)(k0 + r) * DIM + n0 + c);
        T[c + 0][r] = f2bf(f.x); T[c + 1][r] = f2bf(f.y);
        T[c + 2][r] = f2bf(f.z); T[c + 3][r] = f2bf(f.w);
    }
    __syncthreads();
    #pragma unroll
    for (int p = 0; p < 4; p++) {
        const int rn = p * 16 + (tid >> 4), ck = (tid & 15) * 4;
        u16x4 v = { T[rn][ck], T[rn][ck + 1], T[rn][ck + 2], T[rn][ck + 3] };
        *(u16x4*)(D + (size_t)(n0 + rn) * DIM + k0 + ck) = v;
    }
}

// ---------------- Phase 1: merged-QKV bf16 GEMM, shared-A LDS, 12 waves --------
// qkv_gemm3m: one 768-thread block computes Q, K AND V for a (m0,c0) tile.
// 3 wave-groups of 4; group tg runs gemm3's per-wave compute against a SHARED
// A double-buffer + its own B buffer.
// R13: A-staging spread over waves 0-7 (1 load each) instead of tg0 (2 each):
// per-wave DMA counts 3/3/2 instead of 4/2/2. The per-iter __syncthreads
// drains to the SLOWEST wave; shaving its load count shortens the tail
// (R12 showed VALU/BW halving changed nothing -> drain-tail-bound).
// outputs: Q[bh][n][d] (pre-scaled), K[bh][n][d], Vt[bh][d][n]
__global__ __launch_bounds__(768)
void qkv_gemm3m(const u16* __restrict__ xb, const u16* __restrict__ Wt,
                const float* __restrict__ bq, const float* __restrict__ bk,
                const float* __restrict__ bv, u16* __restrict__ ws) {
    __shared__ u16 As[2][4096];
    __shared__ u16 Bs[3][2][4096];

    const int m0 = blockIdx.x * 128;
    const int c0 = blockIdx.y * 128;

    const int tid  = threadIdx.x;
    const int lane = tid & 63;
    const int w    = tid >> 6;        // 0..11
    const int tg   = w >> 2;          // 0..2  (Q/K/V group)
    const int wl   = w & 3;           // wave within group
    const int wr = wl >> 1, wc = wl & 1;
    const int g = lane >> 4, ln = lane & 15;

    const u16* Wtb = Wt + (size_t)tg * DIM * DIM;
    const float* bias = (tg == 0) ? bq : (tg == 1) ? bk : bv;
    const float osc = (tg == 0) ? QSCALE : 1.0f;
    u16* dst = ws + (size_t)tg * ((size_t)MM * DIM);

    floatx4 acc[4][4];
    #pragma unroll
    for (int i = 0; i < 4; i++)
        #pragma unroll
        for (int j = 0; j < 4; j++) acc[i][j] = (floatx4){0.f,0.f,0.f,0.f};

    const int gseg = (lane & 3) ^ ((lane >> 3) & 3);
    // A-staging: wave w (w<8) covers rows w*16..w*16+15 -> As[buf][w*512]
    const u16* gAw = xb + (size_t)(m0 + w*16 + (lane >> 2)) * DIM + gseg*8;
    // B-staging: each tg's 4 waves cover their own B panel (2 loads each)
    const int srow = wl*16 + (lane >> 2);
    const u16* gB = Wtb + (size_t)(c0 + srow) * DIM + gseg*8;

    // stage tile 0
    if (w < 8) async_copy16(gAw, &As[0][w*512]);
    async_copy16(gB,                  &Bs[tg][0][wl*512]);
    async_copy16(gB + (size_t)64*DIM, &Bs[tg][0][2048 + wl*512]);
    __syncthreads();

    const int xu = (ln >> 1) & 3;

    for (int it = 0; it < 32; it++) {
        const int cur = it & 1;
        if (it < 31) {
            const int nxt = cur ^ 1;
            const int kk = (it + 1) * 32;
            if (w < 8) async_copy16(gAw + kk, &As[nxt][w*512]);
            async_copy16(gB + kk,                  &Bs[tg][nxt][wl*512]);
            async_copy16(gB + kk + (size_t)64*DIM, &Bs[tg][nxt][2048 + wl*512]);
        }

        bf16x8 a[4], b[4];
        #pragma unroll
        for (int fr = 0; fr < 4; fr++)
            a[fr] = ldb8(&As[cur][(wr*64 + fr*16 + ln)*32 + (g ^ xu)*8]);
        #pragma unroll
        for (int fc = 0; fc < 4; fc++)
            b[fc] = ldb8(&Bs[tg][cur][(wc*64 + fc*16 + ln)*32 + (g ^ xu)*8]);

        if (tg < 2) {
            #pragma unroll
            for (int fr = 0; fr < 4; fr++)
                #pragma unroll
                for (int fc = 0; fc < 4; fc++)
                    acc[fr][fc] = __builtin_amdgcn_mfma_f32_16x16x32_bf16(
                        b[fc], a[fr], acc[fr][fc], 0, 0, 0);
        } else {
            #pragma unroll
            for (int fr = 0; fr < 4; fr++)
                #pragma unroll
                for (int fc = 0; fc < 4; fc++)
                    acc[fr][fc] = __builtin_amdgcn_mfma_f32_16x16x32_bf16(
                        a[fr], b[fc], acc[fr][fc], 0, 0, 0);
        }
        __syncthreads();
    }

    if (tg < 2) {
        #pragma unroll
        for (int fc = 0; fc < 4; fc++) {
            const int cc = c0 + wc*64 + fc*16 + g*4;
            const float4 b4 = *(const float4*)&bias[cc];
            const int h = cc >> 6, d = cc & 63;
            #pragma unroll
            for (int fr = 0; fr < 4; fr++) {
                const int tok = m0 + wr*64 + fr*16 + ln;
                const int bidx = tok >> 11, nn = tok & 2047;
                u16x4 v = { f2bf((acc[fr][fc][0] + b4.x) * osc),
                            f2bf((acc[fr][fc][1] + b4.y) * osc),
                            f2bf((acc[fr][fc][2] + b4.z) * osc),
                            f2bf((acc[fr][fc][3] + b4.w) * osc) };
                *(u16x4*)&dst[((size_t)(bidx*NH + h)*SEQ + nn)*DH + d] = v;
            }
        }
    } else {
        #pragma unroll
        for (int fc = 0; fc < 4; fc++) {
            const int cc = c0 + wc*64 + fc*16 + ln;
            const float bias_v = bias[cc];
            const int h = cc >> 6, d = cc & 63;
            #pragma unroll
            for (int fr = 0; fr < 4; fr++) {
                const int mrow = m0 + wr*64 + fr*16 + g*4;
                const int bidx = mrow >> 11, nn = mrow & 2047;
                u16x4 v = { f2bf(acc[fr][fc][0] + bias_v), f2bf(acc[fr][fc][1] + bias_v),
                            f2bf(acc[fr][fc][2] + bias_v), f2bf(acc[fr][fc][3] + bias_v) };
                *(u16x4*)&dst[((size_t)(bidx*NH + h)*DH + d)*SEQ + nn] = v;
            }
        }
    }
}

// ---------------- Phase 1 (fallback, fp32 inputs, small ws) ----------------
#define LDA 40
__global__ __launch_bounds__(256)
void qkv_gemm(const float* __restrict__ x,
              const float* __restrict__ Wq, const float* __restrict__ bq,
              const float* __restrict__ Wk, const float* __restrict__ bk,
              const float* __restrict__ Wv, const float* __restrict__ bv,
              u16* __restrict__ ws) {
    __shared__ u16 As[128 * LDA];
    __shared__ u16 Bs[128 * LDA];
    const int m0 = blockIdx.x * 128;
    const int t  = blockIdx.y >> 3;
    const int c0 = (blockIdx.y & 7) * 128;
    const float* W    = (t == 0) ? Wq : (t == 1) ? Wk : Wv;
    const float* bias = (t == 0) ? bq : (t == 1) ? bk : bv;
    const float osc = (t == 0) ? QSCALE : 1.0f;
    u16* dst = ws + (size_t)t * ((size_t)MM * DIM);
    const int tid  = threadIdx.x;
    const int lane = tid & 63;
    const int wave = tid >> 6;
    const int wr = wave >> 1, wc = wave & 1;
    const int g = lane >> 4, ln = lane & 15;
    floatx4 acc[4][4];
    #pragma unroll
    for (int i = 0; i < 4; i++)
        #pragma unroll
        for (int j = 0; j < 4; j++) acc[i][j] = (floatx4){0.f,0.f,0.f,0.f};
    const int ar  = tid >> 1;
    const int ak  = (tid & 1) * 16;
    const int bkr = tid & 31;
    const int bc  = (tid >> 5) * 16;
    for (int kk = 0; kk < DIM; kk += 32) {
        {
            const float4* s4 = (const float4*)(x + (size_t)(m0 + ar) * DIM + kk + ak);
            float4 f0 = s4[0], f1 = s4[1], f2 = s4[2], f3 = s4[3];
            unsigned pk[8];
            pk[0] = f2bf(f0.x) | ((unsigned)f2bf(f0.y) << 16);
            pk[1] = f2bf(f0.z) | ((unsigned)f2bf(f0.w) << 16);
            pk[2] = f2bf(f1.x) | ((unsigned)f2bf(f1.y) << 16);
            pk[3] = f2bf(f1.z) | ((unsigned)f2bf(f1.w) << 16);
            pk[4] = f2bf(f2.x) | ((unsigned)f2bf(f2.y) << 16);
            pk[5] = f2bf(f2.z) | ((unsigned)f2bf(f2.w) << 16);
            pk[6] = f2bf(f3.x) | ((unsigned)f2bf(f3.y) << 16);
            pk[7] = f2bf(f3.z) | ((unsigned)f2bf(f3.w) << 16);
            uint4* d = (uint4*)&As[ar * LDA + ak];
            d[0] = make_uint4(pk[0], pk[1], pk[2], pk[3]);
            d[1] = make_uint4(pk[4], pk[5], pk[6], pk[7]);
        }
        {
            const float4* s4 = (const float4*)(W + (size_t)(kk + bkr) * DIM + c0 + bc);
            float4 f0 = s4[0], f1 = s4[1], f2 = s4[2], f3 = s4[3];
            float fv[16] = {f0.x,f0.y,f0.z,f0.w, f1.x,f1.y,f1.z,f1.w,
                            f2.x,f2.y,f2.z,f2.w, f3.x,f3.y,f3.z,f3.w};
            #pragma unroll
            for (int j = 0; j < 16; j++)
                Bs[(bc + j) * LDA + bkr] = f2bf(fv[j]);
        }
        __syncthreads();
        bf16x8 a[4], b[4];
        #pragma unroll
        for (int fr = 0; fr < 4; fr++)
            a[fr] = ldb8(&As[(wr*64 + fr*16 + ln) * LDA + g*8]);
        #pragma unroll
        for (int fc = 0; fc < 4; fc++)
            b[fc] = ldb8(&Bs[(wc*64 + fc*16 + ln) * LDA + g*8]);
        #pragma unroll
        for (int fr = 0; fr < 4; fr++)
            #pragma unroll
            for (int fc = 0; fc < 4; fc++)
                acc[fr][fc] = __builtin_amdgcn_mfma_f32_16x16x32_bf16(
                    a[fr], b[fc], acc[fr][fc], 0, 0, 0);
        __syncthreads();
    }
    #pragma unroll
    for (int fc = 0; fc < 4; fc++) {
        const int cc = c0 + wc*64 + fc*16 + ln;
        const float bias_v = bias[cc];
        const int h = cc >> 6, d = cc & 63;
        #pragma unroll
        for (int fr = 0; fr < 4; fr++) {
            #pragma unroll
            for (int rr = 0; rr < 4; rr++) {
                const int mrow = m0 + wr*64 + fr*16 + g*4 + rr;
                const int bidx = mrow >> 11, nn = mrow & 2047;
                const float val = (acc[fr][fc][rr] + bias_v) * osc;
                size_t idx;
                if (t < 2) idx = ((size_t)(bidx*NH + h)*SEQ + nn)*DH + d;
                else       idx = ((size_t)(bidx*NH + h)*DH + d)*SEQ + nn;
                dst[idx] = f2bf(val);
            }
        }
    }
}

// ---------------- Phase 2: flash attention, 64 q-rows/wave, in-register P ------
// attn11 (best measured: 83.7-84.2 us): dual q-set compute sharing each K/V
// fragment read, 4-buffer depth-3 counted-vmcnt staging, XCD-aware grid,
// cvt_pk P pack. (setprio and 512-row variants both regressed; kept frozen.)
__global__ __launch_bounds__(256, 2)
void attn11(const u16* __restrict__ ws, float* __restrict__ out) {
    const int bid = blockIdx.x;
    const int qt = bid >> 6;       // 0..7
    const int bh = bid & 63;       // same-XCD group (id mod 8 == bh mod 8)
    const int b  = bh >> 4;
    const int h  = bh & 15;

    const u16* Qw = ws;
    const u16* Kw = ws + (size_t)MM * DIM;
    const u16* Vt = ws + 2 * (size_t)MM * DIM;

    __shared__ u16 Kbuf[4][4096];   // [64 keys][64 d], 16B-unit XOR swizzle
    __shared__ u16 Vbuf[4][4096];   // [64 d][64 keys], same swizzle

    const int tid  = threadIdx.x;
    const int lane = tid & 63;
    const int w    = tid >> 6;          // 0..3
    const int l31  = lane & 31;
    const int hi   = lane >> 5;
    const int c7   = lane & 7;
    const int q0w  = qt*256 + w*64;

    // staging: wave w covers rows w*16..w*16+15 (two 16B copies per lane per buf)
    const int srow = w*16 + (lane >> 3);
    const int sseg = (lane & 7) ^ ((lane >> 3) & 7);
    const u16* kg = Kw + ((size_t)bh*SEQ + srow)*DH + sseg*8;
    const u16* vg = Vt + ((size_t)bh*DH + srow)*SEQ + sseg*8;

    // Q fragments, two q-sets: lane holds q=l31 (+qs*32), d = ds*16 + hi*8 + j
    bf16x8 qf[2][4];
    #pragma unroll
    for (int qs = 0; qs < 2; qs++) {
        const u16* qp = Qw + ((size_t)bh*SEQ + q0w + qs*32 + l31)*DH + hi*8;
        #pragma unroll
        for (int ds = 0; ds < 4; ds++) qf[qs][ds] = ldb8(qp + ds*16);
    }

    floatx16 accO[2][2];   // [qs][fd]
    #pragma unroll
    for (int qs = 0; qs < 2; qs++)
        #pragma unroll
        for (int fd = 0; fd < 2; fd++)
            #pragma unroll
            for (int r = 0; r < 16; r++) accO[qs][fd][r] = 0.f;
    floatx2 lr2[2] = { (floatx2){0.f,0.f}, (floatx2){0.f,0.f} };
    floatx16 fz;
    #pragma unroll
    for (int r = 0; r < 16; r++) fz[r] = 0.f;

    // prologue: stage tiles 0,1,2 (per wave: 2 K + 2 V loads per tile)
    #pragma unroll
    for (int t = 0; t < 3; t++) {
        async_copy16(kg + (size_t)t*64*DH,           &Kbuf[t][w*1024]);
        async_copy16(kg + (size_t)t*64*DH + 8*DH,    &Kbuf[t][w*1024 + 512]);
        async_copy16(vg + (size_t)t*64,              &Vbuf[t][w*1024]);
        async_copy16(vg + (size_t)t*64 + (size_t)8*SEQ, &Vbuf[t][w*1024 + 512]);
    }

    for (int kt = 0; kt < 32; kt++) {
        // tile kt's 4 loads complete; tiles kt+1,kt+2 (8 loads) stay in flight
        if (kt < 30)       asm volatile("s_waitcnt vmcnt(8)" ::: "memory");
        else if (kt == 30) asm volatile("s_waitcnt vmcnt(4)" ::: "memory");
        else               asm volatile("s_waitcnt vmcnt(0)" ::: "memory");
        __builtin_amdgcn_s_barrier();
        __builtin_amdgcn_sched_barrier(0);

        // issue tile kt+3 into buf[(kt+3)&3] (read last at iter kt-1, safe now)
        if (kt < 29) {
            const int t3 = kt + 3;
            async_copy16(kg + (size_t)t3*64*DH,           &Kbuf[t3 & 3][w*1024]);
            async_copy16(kg + (size_t)t3*64*DH + 8*DH,    &Kbuf[t3 & 3][w*1024 + 512]);
            async_copy16(vg + (size_t)t3*64,              &Vbuf[t3 & 3][w*1024]);
            async_copy16(vg + (size_t)t3*64 + (size_t)8*SEQ, &Vbuf[t3 & 3][w*1024 + 512]);
        }

        const u16* Kc = &Kbuf[kt & 3][0];
        const u16* Vc = &Vbuf[kt & 3][0];

        #pragma unroll
        for (int kb = 0; kb < 2; kb++) {
            // ---- K fragments (shared by both q-sets): 4 b128 reads
            const u16* krow = &Kc[(kb*32 + l31)*64];
            bf16x8 kf0 = ldb8(&krow[((0 + hi) ^ c7)*8]);
            bf16x8 kf1 = ldb8(&krow[((2 + hi) ^ c7)*8]);
            bf16x8 kf2 = ldb8(&krow[((4 + hi) ^ c7)*8]);
            bf16x8 kf3 = ldb8(&krow[((6 + hi) ^ c7)*8]);

            // ---- QK^T: two independent 32x32 score tiles off the same K frags
            floatx16 z0 = mfma32(kf0, qf[0][0], fz);
            floatx16 z1 = mfma32(kf0, qf[1][0], fz);
            z0 = mfma32(kf1, qf[0][1], z0);
            z1 = mfma32(kf1, qf[1][1], z1);
            z0 = mfma32(kf2, qf[0][2], z0);
            z1 = mfma32(kf2, qf[1][2], z1);
            z0 = mfma32(kf3, qf[0][3], z0);
            z1 = mfma32(kf3, qf[1][3], z1);

            // ---- softmax numerator + pack, per q-set
            union { unsigned u[4]; bf16x8 v; } bpA0, bpA1, bpB0, bpB1;
            {
                float p[16];
                #pragma unroll
                for (int r = 0; r < 16; r++) p[r] = __builtin_amdgcn_exp2f(z0[r]);
                #pragma unroll
                for (int i = 0; i < 8; i++) lr2[0] += (floatx2){p[2*i], p[2*i+1]};
                unsigned c[8];
                #pragma unroll
                for (int i = 0; i < 8; i++) c[i] = cvtpk(p[2*i], p[2*i+1]);
                uint2v s02 = __builtin_amdgcn_permlane32_swap(c[0], c[2], false, false);
                uint2v s13 = __builtin_amdgcn_permlane32_swap(c[1], c[3], false, false);
                uint2v s46 = __builtin_amdgcn_permlane32_swap(c[4], c[6], false, false);
                uint2v s57 = __builtin_amdgcn_permlane32_swap(c[5], c[7], false, false);
                bpA0.u[0] = s02[0]; bpA0.u[1] = s13[0]; bpA0.u[2] = s02[1]; bpA0.u[3] = s13[1];
                bpA1.u[0] = s46[0]; bpA1.u[1] = s57[0]; bpA1.u[2] = s46[1]; bpA1.u[3] = s57[1];
            }
            {
                float p[16];
                #pragma unroll
                for (int r = 0; r < 16; r++) p[r] = __builtin_amdgcn_exp2f(z1[r]);
                #pragma unroll
                for (int i = 0; i < 8; i++) lr2[1] += (floatx2){p[2*i], p[2*i+1]};
                unsigned c[8];
                #pragma unroll
                for (int i = 0; i < 8; i++) c[i] = cvtpk(p[2*i], p[2*i+1]);
                uint2v s02 = __builtin_amdgcn_permlane32_swap(c[0], c[2], false, false);
                uint2v s13 = __builtin_amdgcn_permlane32_swap(c[1], c[3], false, false);
                uint2v s46 = __builtin_amdgcn_permlane32_swap(c[4], c[6], false, false);
                uint2v s57 = __builtin_amdgcn_permlane32_swap(c[5], c[7], false, false);
                bpB0.u[0] = s02[0]; bpB0.u[1] = s13[0]; bpB0.u[2] = s02[1]; bpB0.u[3] = s13[1];
                bpB1.u[0] = s46[0]; bpB1.u[1] = s57[0]; bpB1.u[2] = s46[1]; bpB1.u[3] = s57[1];
            }

            // ---- V fragments (shared): 4 b128 reads; PV for both q-sets
            bf16x8 av00 = ldb8(&Vc[(0*32 + l31)*64 + ((kb*4 + 0 + hi) ^ c7)*8]);
            bf16x8 av01 = ldb8(&Vc[(0*32 + l31)*64 + ((kb*4 + 2 + hi) ^ c7)*8]);
            bf16x8 av10 = ldb8(&Vc[(1*32 + l31)*64 + ((kb*4 + 0 + hi) ^ c7)*8]);
            bf16x8 av11 = ldb8(&Vc[(1*32 + l31)*64 + ((kb*4 + 2 + hi) ^ c7)*8]);
            accO[0][0] = mfma32(av00, bpA0.v, accO[0][0]);
            accO[1][0] = mfma32(av00, bpB0.v, accO[1][0]);
            accO[0][1] = mfma32(av10, bpA0.v, accO[0][1]);
            accO[1][1] = mfma32(av10, bpB0.v, accO[1][1]);
            accO[0][0] = mfma32(av01, bpA1.v, accO[0][0]);
            accO[1][0] = mfma32(av01, bpB1.v, accO[1][0]);
            accO[0][1] = mfma32(av11, bpA1.v, accO[0][1]);
            accO[1][1] = mfma32(av11, bpB1.v, accO[1][1]);
        }
    }

    // ---- epilogue: per q-set row-sum across hi halves, normalize, write
    #pragma unroll
    for (int qs = 0; qs < 2; qs++) {
        float v = lr2[qs][0] + lr2[qs][1];
        v += __shfl_xor(v, 32, 64);
        const float inv = 1.0f / v;
        const int n = q0w + qs*32 + l31;
        float* orow = &out[((size_t)b*SEQ + n)*DIM + h*DH];
        #pragma unroll
        for (int fd = 0; fd < 2; fd++)
            #pragma unroll
            for (int rp = 0; rp < 4; rp++) {
                const int d = fd*32 + rp*8 + hi*4;
                float4 o = { accO[qs][fd][rp*4+0]*inv, accO[qs][fd][rp*4+1]*inv,
                             accO[qs][fd][rp*4+2]*inv, accO[qs][fd][rp*4+3]*inv };
                *(float4*)&orow[d] = o;
            }
    }
}

extern "C" void kernel_launch(void* const* d_in, const int* in_sizes, int n_in,
                              void* d_out, int out_size, void* d_ws, size_t ws_size,
                              hipStream_t stream) {
    const float* x  = (const float*)d_in[0];
    const float* Wq = (const float*)d_in[1];
    const float* bq = (const float*)d_in[2];
    const float* Wk = (const float*)d_in[3];
    const float* bk = (const float*)d_in[4];
    const float* Wv = (const float*)d_in[5];
    const float* bv = (const float*)d_in[6];
    u16* ws = (u16*)d_ws;
    float* out = (float*)d_out;

    const size_t need = (size_t)4 * MM * DIM * 2 + (size_t)3 * DIM * DIM * 2;
    if (ws_size >= need) {
        u16* xb = ws + (size_t)3 * MM * DIM;
        u16* Wt = ws + (size_t)4 * MM * DIM;
        prep<<<dim3(8192 + 768), 256, 0, stream>>>(x, xb, Wq, Wk, Wv, Wt);
        qkv_gemm3m<<<dim3(MM/128, 8), 768, 0, stream>>>(xb, Wt, bq, bk, bv, ws);
    } else {
        qkv_gemm<<<dim3(MM/128, 24), 256, 0, stream>>>(x, Wq, bq, Wk, bk, Wv, bv, ws);
    }
    attn11<<<dim3((SEQ/256) * NH * BB), 256, 0, stream>>>(ws, out);
}